// Round 5
// baseline (248.112 us; speedup 1.0000x reference)
//
#include <hip/hip_runtime.h>

typedef __attribute__((ext_vector_type(8))) short s8v;
typedef __attribute__((ext_vector_type(16))) float f16vf;
typedef __attribute__((ext_vector_type(4))) unsigned int u4v;
typedef __attribute__((ext_vector_type(2))) unsigned int u2v;

static __device__ __forceinline__ unsigned short f2b(float f) {
  unsigned int u = __builtin_bit_cast(unsigned int, f);
  u += 0x7fffu + ((u >> 16) & 1u);  // RNE
  return (unsigned short)(u >> 16);
}

#if defined(__has_builtin)
#if __has_builtin(__builtin_amdgcn_cvt_pk_bf16_f32)
#define HAVE_PK_BF16 1
#endif
#endif

// pack two floats -> bf16x2 dword (lo = a, hi = b)
static __device__ __forceinline__ unsigned int pk2(float a, float b) {
#ifdef HAVE_PK_BF16
  auto r = __builtin_amdgcn_cvt_pk_bf16_f32(a, b);
  static_assert(sizeof(r) == 4, "pk bf16 size");
  return __builtin_bit_cast(unsigned int, r);
#else
  return (unsigned int)f2b(a) | ((unsigned int)f2b(b) << 16);
#endif
}

static __device__ __forceinline__ float blo(unsigned int u) {
  return __builtin_bit_cast(float, u << 16);
}
static __device__ __forceinline__ float bhi(unsigned int u) {
  return __builtin_bit_cast(float, u & 0xffff0000u);
}

// async global->LDS DMA, 16B/lane; LDS dest wave-uniform base + lane*16
static __device__ __forceinline__ void dma16(const void* g, void* l) {
  auto gp = reinterpret_cast<const __attribute__((address_space(1))) unsigned int*>(
      reinterpret_cast<uintptr_t>(g));
  auto lp = reinterpret_cast<__attribute__((address_space(3))) unsigned int*>(
      (unsigned int)reinterpret_cast<uintptr_t>(l));
  __builtin_amdgcn_global_load_lds(gp, lp, 16, 0, 0);
}

// ---------------- pre-pass: pack K / V^T into slot-major 32-key tiles ------
// K tile (bk,kt32): 16 slots(s=d/8) x 32 keys(t) x 16B: elem = s*256 + t*8
// V tile (bk,kt32): 4 slots(s=t/8) x 128 dims(d) x 16B: elem = s*1024 + d*8
__global__ __launch_bounds__(256) void prepack_kernel(
    const float* __restrict__ K, const float* __restrict__ V,
    unsigned short* __restrict__ Kt, unsigned short* __restrict__ Vt) {
  const int bx = blockIdx.x;
  const int tile = bx & 511;  // bk*32 + kb64
  const int bk = tile >> 5, kb = tile & 31;
  const int tid = threadIdx.x;
  if (bx < 512) {
    const float* src = K + ((size_t)bk * 2048 + kb * 64) * 128;
    unsigned short* dst = Kt + ((size_t)bk * 64 + kb * 2) * 4096;
#pragma unroll
    for (int i = 0; i < 4; ++i) {
      const int task = tid + 256 * i;  // 1024 = 64 rows x 16 slots
      const int row = task >> 4, slot = task & 15;
      const float* s = src + row * 128 + slot * 8;
      const float4 a = *(const float4*)s;
      const float4 b = *(const float4*)(s + 4);
      u4v o = (u4v){pk2(a.x, a.y), pk2(a.z, a.w), pk2(b.x, b.y), pk2(b.z, b.w)};
      const int t32 = row >> 5, r = row & 31;
      *(u4v*)&dst[t32 * 4096 + slot * 256 + r * 8] = o;
    }
  } else {
    // V: 4x4 register-block transpose
    const float* src = V + ((size_t)bk * 2048 + kb * 64) * 128;
    unsigned short* dst = Vt + ((size_t)bk * 64 + kb * 2) * 4096;
    const int vtq = tid >> 4, vdq0 = tid & 15;
#pragma unroll
    for (int u = 0; u < 2; ++u) {
      const int d0 = 4 * (vdq0 + 16 * u), t0 = 4 * vtq;  // t0 in 0..60
      const float* vr = src + (size_t)t0 * 128 + d0;
      const float4 r0 = *(const float4*)(vr);
      const float4 r1 = *(const float4*)(vr + 128);
      const float4 r2 = *(const float4*)(vr + 256);
      const float4 r3 = *(const float4*)(vr + 384);
      const float* f0 = (const float*)&r0;
      const float* f1 = (const float*)&r1;
      const float* f2 = (const float*)&r2;
      const float* f3 = (const float*)&r3;
      const int t32 = t0 >> 5, tt = t0 & 31;
      const int sl = tt >> 3, j0 = tt & 7;  // j0 in {0,4}
#pragma unroll
      for (int c = 0; c < 4; ++c) {
        const int d = d0 + c;
        *(u2v*)&dst[t32 * 4096 + sl * 1024 + d * 8 + j0] =
            (u2v){pk2(f0[c], f1[c]), pk2(f2[c], f3[c])};
      }
    }
  }
}

// ---------------- attention kernel (split-K, constant-ref softmax) ---------
__global__ __launch_bounds__(256, 4) void gqa_attn_kernel(
    const float* __restrict__ Q, const unsigned short* __restrict__ Kt,
    const unsigned short* __restrict__ Vt, unsigned short* __restrict__ Op,
    float* __restrict__ Lp) {
  constexpr float QS = 0.08838834764831845f * 1.4426950408889634f;  // 1/sqrt(128)*log2e
  constexpr float CREF = 12.0f;  // constant softmax reference (scores*log2e ~ +-8.5)

  __shared__ unsigned short sh[16384];  // 32KB: K bufs @ {0,8192}, V bufs @ 16384+{0,8192}
  char* shc = (char*)sh;

  const int tid = threadIdx.x;
  const int l = tid & 63, w = tid >> 6;
  const int col = l & 31, hh = l >> 5;
  const bool h1 = hh != 0;

  const int bx = blockIdx.x;
  const int bh = bx & 31;            // b*16 + h
  const int g = (bx >> 5) & 15;
  const int split = bx >> 9;         // key-range half
  const int qt = (g < 8) ? (15 - g) : (g - 8);  // zigzag, heavy first
  const int b = bh >> 4, h = bh & 15;
  const int bk = b * 8 + (h >> 1);

  const float* Qb = Q + ((size_t)bh * 2048) * 128;
  const unsigned short* Ktb = Kt + ((size_t)bk * 64) * 4096;
  const unsigned short* Vtb = Vt + ((size_t)bk * 64) * 4096;

  const int nloc = 2 * qt + 2;       // 32-key tiles per split (even)
  const int k0 = split * nloc;
  const int kend = k0 + nloc;

  // vaddr bases: all other address terms are compile-time ds_read immediates
  const int vK = col * 16 + hh * 512;
  const int vV = col * 16 + hh * 2048;

  auto stage = [&](int kt, int bo) {
    const unsigned short* kg = Ktb + (size_t)kt * 4096;
    const unsigned short* vg = Vtb + (size_t)kt * 4096;
#pragma unroll
    for (int c = 0; c < 2; ++c) {
      const int chunk = 2 * w + c;  // 8 x 1KB chunks per 8KB tile
      dma16(kg + chunk * 512 + l * 8, shc + bo + chunk * 1024);
      dma16(vg + chunk * 512 + l * 8, shc + 16384 + bo + chunk * 1024);
    }
  };

  stage(k0, 0);  // DMA overlaps Q-fragment conversion

  // Q fragments (B-operand): lane holds Q[q=col][d=16ks+8hh+j], pre-scaled
  const int qrow = qt * 128 + w * 32 + col;
  const float* qp = Qb + (size_t)qrow * 128;
  s8v qf[8];
#pragma unroll
  for (int ks = 0; ks < 8; ++ks) {
    const float4 x = *(const float4*)(qp + 16 * ks + 8 * hh);
    const float4 y = *(const float4*)(qp + 16 * ks + 8 * hh + 4);
    u4v q4 = (u4v){pk2(x.x * QS, x.y * QS), pk2(x.z * QS, x.w * QS),
                   pk2(y.x * QS, y.y * QS), pk2(y.z * QS, y.w * QS)};
    qf[ks] = __builtin_bit_cast(s8v, q4);
  }

  f16vf oacc[4];  // O^T: oacc[dblk][r] = Ou[q=col][d=32dblk+(r&3)+8(r>>2)+4hh]
#pragma unroll
  for (int i = 0; i < 4; ++i)
#pragma unroll
    for (int j = 0; j < 16; ++j) oacc[i][j] = 0.f;
  float l_i = 0.f;

  __syncthreads();  // first DMA landed

  auto body = [&](int kt, int bo) {
    const bool more = (kt + 1 < kend);
    if (more) stage(kt + 1, bo ^ 8192);  // DMA in flight during compute

    // ---- S^T - C = K*Q^T - C (C folded into accumulator init)
    f16vf sT;
#pragma unroll
    for (int j = 0; j < 16; ++j) sT[j] = -CREF;
#pragma unroll
    for (int ks = 0; ks < 8; ++ks) {
      s8v kf = *(const s8v*)(shc + vK + (bo + ks * 1024));
      sT = __builtin_amdgcn_mfma_f32_32x32x16_bf16(kf, qf[ks], sT, 0, 0, 0);
    }

    // ---- causal mask (only last 4 tiles can cross the diagonal)
    if (kt >= 4 * qt) {
#pragma unroll
      for (int j = 0; j < 16; ++j) {
        const int key = kt * 32 + (j & 3) + 8 * (j >> 2) + 4 * hh;
        if (key > qrow) sT[j] = -1e30f;
      }
    }

    // ---- p = exp2(s - C); pack; accumulate l (per-half, no cross-lane)
    unsigned int pdw[8];
    float ps0 = 0.f, ps1 = 0.f;
#pragma unroll
    for (int q = 0; q < 8; ++q) {
      const float p0 = __builtin_amdgcn_exp2f(sT[2 * q]);
      const float p1 = __builtin_amdgcn_exp2f(sT[2 * q + 1]);
      pdw[q] = pk2(p0, p1);
      if (q & 1) ps1 += p0 + p1; else ps0 += p0 + p1;
    }
    l_i += ps0 + ps1;

    // ---- PV: P^T B-fragments via half-wave exchange; Ou^T += V^T P^T
#pragma unroll
    for (int ksp = 0; ksp < 2; ++ksp) {
      const int e4 = ksp * 4;
      const unsigned int own0 = h1 ? pdw[e4 + 2] : pdw[e4 + 0];
      const unsigned int own1 = h1 ? pdw[e4 + 3] : pdw[e4 + 1];
      const unsigned int snd0 = h1 ? pdw[e4 + 0] : pdw[e4 + 2];
      const unsigned int snd1 = h1 ? pdw[e4 + 1] : pdw[e4 + 3];
      const unsigned int rcv0 = (unsigned int)__shfl_xor((int)snd0, 32);
      const unsigned int rcv1 = (unsigned int)__shfl_xor((int)snd1, 32);
      u4v pw;
      pw[0] = h1 ? rcv0 : own0;
      pw[1] = h1 ? rcv1 : own1;
      pw[2] = h1 ? own0 : rcv0;
      pw[3] = h1 ? own1 : rcv1;
      s8v pf = __builtin_bit_cast(s8v, pw);
#pragma unroll
      for (int dblk = 0; dblk < 4; ++dblk) {
        s8v vf = *(const s8v*)(shc + vV + (16384 + bo + ksp * 4096 + dblk * 512));
        oacc[dblk] = __builtin_amdgcn_mfma_f32_32x32x16_bf16(vf, pf, oacc[dblk], 0, 0, 0);
      }
    }

    if (more) __syncthreads();  // drain DMA(kt+1) + guard buffer reuse
  };

  for (int li = 0; li < nloc; li += 2) {
    body(k0 + li, 0);
    body(k0 + li + 1, 8192);
  }

  // ---- epilogue: write unnormalized Ou (bf16) and l (fp32) partials
  const float lt = l_i + __shfl_xor(l_i, 32);
  const size_t prow = (size_t)(split * 512 + bh * 16 + qt) * 128 + (w * 32 + col);
  unsigned short* op = Op + prow * 128;
#pragma unroll
  for (int dblk = 0; dblk < 4; ++dblk)
#pragma unroll
    for (int gg = 0; gg < 4; ++gg) {
      u2v st = (u2v){pk2(oacc[dblk][4 * gg + 0], oacc[dblk][4 * gg + 1]),
                     pk2(oacc[dblk][4 * gg + 2], oacc[dblk][4 * gg + 3])};
      *(u2v*)(op + dblk * 32 + 8 * gg + 4 * hh) = st;
    }
  if (!h1) Lp[prow] = lt;
}

// ---------------- combine: O = (Ou0 + Ou1) / (l0 + l1) --------------------
__global__ __launch_bounds__(256) void combine_kernel(
    const unsigned short* __restrict__ Op, const float* __restrict__ Lp,
    float* __restrict__ O) {
  const int blk = blockIdx.x;  // bh*16 + qt
  const int tid = threadIdx.x;
  const int q = tid >> 1, hf = tid & 1;
  const size_t row = (size_t)blk * 128 + q;
  const float l0 = Lp[row];
  const float l1 = Lp[row + 65536];
  const float inv = 1.0f / (l0 + l1);  // l0 > 0 always (diagonal key in split 0)
  const unsigned short* p0 = Op + row * 128 + hf * 64;
  const unsigned short* p1 = p0 + (size_t)512 * 128 * 128;
  const int bh = blk >> 4, qt = blk & 15;
  float* out = O + ((size_t)bh * 2048 + qt * 128 + q) * 128 + hf * 64;
#pragma unroll
  for (int i = 0; i < 8; ++i) {
    u4v a = *(const u4v*)(p0 + i * 8);
    u4v b = *(const u4v*)(p1 + i * 8);
    float4 s0, s1;
    s0.x = (blo(a[0]) + blo(b[0])) * inv;
    s0.y = (bhi(a[0]) + bhi(b[0])) * inv;
    s0.z = (blo(a[1]) + blo(b[1])) * inv;
    s0.w = (bhi(a[1]) + bhi(b[1])) * inv;
    s1.x = (blo(a[2]) + blo(b[2])) * inv;
    s1.y = (bhi(a[2]) + bhi(b[2])) * inv;
    s1.z = (blo(a[3]) + blo(b[3])) * inv;
    s1.w = (bhi(a[3]) + bhi(b[3])) * inv;
    *(float4*)(out + i * 8) = s0;
    *(float4*)(out + i * 8 + 4) = s1;
  }
}

extern "C" void kernel_launch(void* const* d_in, const int* in_sizes, int n_in,
                              void* d_out, int out_size, void* d_ws, size_t ws_size,
                              hipStream_t stream) {
  const float* q = (const float*)d_in[0];
  const float* k = (const float*)d_in[1];
  const float* v = (const float*)d_in[2];
  float* o = (float*)d_out;
  unsigned short* Kt = (unsigned short*)d_ws;             // 8MB
  unsigned short* Vt = Kt + (size_t)16 * 64 * 4096;       // +8MB
  unsigned short* Op = Vt + (size_t)16 * 64 * 4096;       // +33.5MB (2 splits)
  float* Lp = (float*)(Op + (size_t)2 * 512 * 128 * 128); // +0.5MB
  prepack_kernel<<<dim3(1024), dim3(256), 0, stream>>>(k, v, Kt, Vt);
  gqa_attn_kernel<<<dim3(1024), dim3(256), 0, stream>>>(q, Kt, Vt, Op, Lp);
  combine_kernel<<<dim3(512), dim3(256), 0, stream>>>(Op, Lp, o);
}

// Round 6
// 152.128 us; speedup vs baseline: 1.6309x; 1.6309x over previous
//
#include <hip/hip_runtime.h>

typedef __attribute__((ext_vector_type(8))) short s8v;
typedef __attribute__((ext_vector_type(16))) float f16vf;
typedef __attribute__((ext_vector_type(4))) unsigned int u4v;
typedef __attribute__((ext_vector_type(2))) unsigned int u2v;

static __device__ __forceinline__ unsigned short f2b(float f) {
  unsigned int u = __builtin_bit_cast(unsigned int, f);
  u += 0x7fffu + ((u >> 16) & 1u);  // RNE
  return (unsigned short)(u >> 16);
}

#if defined(__has_builtin)
#if __has_builtin(__builtin_amdgcn_cvt_pk_bf16_f32)
#define HAVE_PK_BF16 1
#endif
#endif

// pack two floats -> bf16x2 dword (lo = a, hi = b)
static __device__ __forceinline__ unsigned int pk2(float a, float b) {
#ifdef HAVE_PK_BF16
  auto r = __builtin_amdgcn_cvt_pk_bf16_f32(a, b);
  static_assert(sizeof(r) == 4, "pk bf16 size");
  return __builtin_bit_cast(unsigned int, r);
#else
  return (unsigned int)f2b(a) | ((unsigned int)f2b(b) << 16);
#endif
}

// async global->LDS DMA, 16B/lane; LDS dest wave-uniform base + lane*16
static __device__ __forceinline__ void dma16(const void* g, void* l) {
  auto gp = reinterpret_cast<const __attribute__((address_space(1))) unsigned int*>(
      reinterpret_cast<uintptr_t>(g));
  auto lp = reinterpret_cast<__attribute__((address_space(3))) unsigned int*>(
      (unsigned int)reinterpret_cast<uintptr_t>(l));
  __builtin_amdgcn_global_load_lds(gp, lp, 16, 0, 0);
}

// ---------------- pre-pass: pack K / V^T into slot-major 32-key tiles ------
// K tile (bk,kt32): 16 slots(s=d/8) x 32 keys(t) x 16B: elem = s*256 + t*8
// V tile (bk,kt32): 4 slots(s=t/8) x 128 dims(d) x 16B: elem = s*1024 + d*8
// (measured R5: this layout gives SQ_LDS_BANK_CONFLICT == 0 in the attn kernel)
__global__ __launch_bounds__(256) void prepack_kernel(
    const float* __restrict__ K, const float* __restrict__ V,
    unsigned short* __restrict__ Kt, unsigned short* __restrict__ Vt) {
  const int bx = blockIdx.x;
  const int tile = bx & 511;  // bk*32 + kb64
  const int bk = tile >> 5, kb = tile & 31;
  const int tid = threadIdx.x;
  if (bx < 512) {
    const float* src = K + ((size_t)bk * 2048 + kb * 64) * 128;
    unsigned short* dst = Kt + ((size_t)bk * 64 + kb * 2) * 4096;
#pragma unroll
    for (int i = 0; i < 4; ++i) {
      const int task = tid + 256 * i;  // 1024 = 64 rows x 16 slots
      const int row = task >> 4, slot = task & 15;
      const float* s = src + row * 128 + slot * 8;
      const float4 a = *(const float4*)s;
      const float4 b = *(const float4*)(s + 4);
      u4v o = (u4v){pk2(a.x, a.y), pk2(a.z, a.w), pk2(b.x, b.y), pk2(b.z, b.w)};
      const int t32 = row >> 5, r = row & 31;
      *(u4v*)&dst[t32 * 4096 + slot * 256 + r * 8] = o;
    }
  } else {
    // V: 4x4 register-block transpose, no LDS
    const float* src = V + ((size_t)bk * 2048 + kb * 64) * 128;
    unsigned short* dst = Vt + ((size_t)bk * 64 + kb * 2) * 4096;
    const int vtq = tid >> 4, vdq0 = tid & 15;
#pragma unroll
    for (int u = 0; u < 2; ++u) {
      const int d0 = 4 * (vdq0 + 16 * u), t0 = 4 * vtq;  // t0 in 0..60
      const float* vr = src + (size_t)t0 * 128 + d0;
      const float4 r0 = *(const float4*)(vr);
      const float4 r1 = *(const float4*)(vr + 128);
      const float4 r2 = *(const float4*)(vr + 256);
      const float4 r3 = *(const float4*)(vr + 384);
      const float* f0 = (const float*)&r0;
      const float* f1 = (const float*)&r1;
      const float* f2 = (const float*)&r2;
      const float* f3 = (const float*)&r3;
      const int t32 = t0 >> 5, tt = t0 & 31;
      const int sl = tt >> 3, j0 = tt & 7;  // j0 in {0,4}
#pragma unroll
      for (int c = 0; c < 4; ++c) {
        const int d = d0 + c;
        *(u2v*)&dst[t32 * 4096 + sl * 1024 + d * 8 + j0] =
            (u2v){pk2(f0[c], f1[c]), pk2(f2[c], f3[c])};
      }
    }
  }
}

// ---------------- attention kernel: CREF softmax, 64-key iters, ILP-2 ------
__global__ __launch_bounds__(256, 2) void gqa_attn_kernel(
    const float* __restrict__ Q, const unsigned short* __restrict__ Kt,
    const unsigned short* __restrict__ Vt, float* __restrict__ O) {
  constexpr float QS = 0.08838834764831845f * 1.4426950408889634f;  // 1/sqrt(128)*log2e
  constexpr float CREF = 12.0f;  // constant softmax reference (scores*log2e ~ +-8.5)

  // 64KB: K 64-tile bufs @ {0,16384}; V 64-tile bufs @ 32768+{0,16384}
  __shared__ unsigned short sh[32768];
  char* shc = (char*)sh;

  const int tid = threadIdx.x;
  const int l = tid & 63, w = tid >> 6;
  const int col = l & 31, hh = l >> 5;
  const bool h1 = hh != 0;

  const int bx = blockIdx.x;
  const int bh = bx & 31;  // b*16 + h  (same-bh blocks share an XCD: L2 reuse)
  const int g = bx >> 5;
  const int qt = (g < 8) ? (15 - g) : (g - 8);  // zigzag pairing, heavy first
  const int b = bh >> 4, h = bh & 15;
  const int bk = b * 8 + (h >> 1);

  const float* Qb = Q + ((size_t)bh * 2048) * 128;
  const unsigned short* Ktb = Kt + ((size_t)bk * 64) * 4096;
  const unsigned short* Vtb = Vt + ((size_t)bk * 64) * 4096;
  float* Ob = O + ((size_t)bh * 2048) * 128;

  // ds_read vaddr bases; everything else is a compile-time immediate
  const int vKb = col * 16 + hh * 512;   // within a 32-key K subtile
  const int vVb = col * 16 + hh * 2048;  // within a 32-key V subtile

  auto stage = [&](int kb, int bo) {  // kb indexes 64-key tiles (16KB each)
    const unsigned short* kg = Ktb + (size_t)kb * 8192;
    const unsigned short* vg = Vtb + (size_t)kb * 8192;
#pragma unroll
    for (int c = 0; c < 4; ++c) {
      const int chunk = 4 * w + c;  // 16 x 1KB chunks per 16KB tile
      dma16(kg + chunk * 512 + l * 8, shc + bo + chunk * 1024);
      dma16(vg + chunk * 512 + l * 8, shc + 32768 + bo + chunk * 1024);
    }
  };

  const int nkb = 2 * qt + 2;  // 64-key tiles, always even
  stage(0, 0);                 // DMA overlaps Q-fragment conversion

  // Q fragments (B-operand): lane holds Q[q=col][d=16ks+8hh+j], pre-scaled
  const int qrow = qt * 128 + w * 32 + col;
  const float* qp = Qb + (size_t)qrow * 128;
  s8v qf[8];
#pragma unroll
  for (int ks = 0; ks < 8; ++ks) {
    const float4 x = *(const float4*)(qp + 16 * ks + 8 * hh);
    const float4 y = *(const float4*)(qp + 16 * ks + 8 * hh + 4);
    u4v q4 = (u4v){pk2(x.x * QS, x.y * QS), pk2(x.z * QS, x.w * QS),
                   pk2(y.x * QS, y.y * QS), pk2(y.z * QS, y.w * QS)};
    qf[ks] = __builtin_bit_cast(s8v, q4);
  }

  f16vf oacc[4];  // O^T: oacc[dblk][r] = Ou[q=col][d=32dblk+(r&3)+8(r>>2)+4hh]
#pragma unroll
  for (int i = 0; i < 4; ++i)
#pragma unroll
    for (int j = 0; j < 16; ++j) oacc[i][j] = 0.f;
  float l_i = 0.f;

  __syncthreads();  // first DMA landed

  auto body = [&](int kb, int bo) {
    const bool more = (kb + 1 < nkb);
    if (more) stage(kb + 1, bo ^ 16384);  // DMA in flight during compute

    // ---- S^T - C for both 32-key subtiles, interleaved (independent chains)
    f16vf sTa, sTb;
#pragma unroll
    for (int j = 0; j < 16; ++j) { sTa[j] = -CREF; sTb[j] = -CREF; }
#pragma unroll
    for (int ks = 0; ks < 8; ++ks) {
      s8v kfa = *(const s8v*)(shc + vKb + (bo + ks * 1024));
      s8v kfb = *(const s8v*)(shc + vKb + (bo + 8192 + ks * 1024));
      sTa = __builtin_amdgcn_mfma_f32_32x32x16_bf16(kfa, qf[ks], sTa, 0, 0, 0);
      sTb = __builtin_amdgcn_mfma_f32_32x32x16_bf16(kfb, qf[ks], sTb, 0, 0, 0);
    }

    // ---- causal mask (last two 64-key tiles only)
    if (kb >= 2 * qt) {
#pragma unroll
      for (int j = 0; j < 16; ++j) {
        const int key = kb * 64 + (j & 3) + 8 * (j >> 2) + 4 * hh;
        if (key > qrow) sTa[j] = -1e30f;
        if (key + 32 > qrow) sTb[j] = -1e30f;
      }
    }

    // ---- p = exp2(s - C); pack; accumulate l (4 chains)
    unsigned int pa[8], pb[8];
    float s0 = 0.f, s1 = 0.f, s2 = 0.f, s3 = 0.f;
#pragma unroll
    for (int q = 0; q < 8; ++q) {
      const float a0 = __builtin_amdgcn_exp2f(sTa[2 * q]);
      const float a1 = __builtin_amdgcn_exp2f(sTa[2 * q + 1]);
      const float b0 = __builtin_amdgcn_exp2f(sTb[2 * q]);
      const float b1 = __builtin_amdgcn_exp2f(sTb[2 * q + 1]);
      pa[q] = pk2(a0, a1);
      pb[q] = pk2(b0, b1);
      if (q & 1) { s1 += a0 + a1; s3 += b0 + b1; }
      else       { s0 += a0 + a1; s2 += b0 + b1; }
    }
    l_i += (s0 + s1) + (s2 + s3);

    // ---- PV: P^T B-fragments via half-wave exchange; Ou^T += V^T P^T
#pragma unroll
    for (int sub = 0; sub < 2; ++sub) {
      const unsigned int* pd = sub ? pb : pa;
      const int vbo = 32768 + bo + sub * 8192;
#pragma unroll
      for (int ksp = 0; ksp < 2; ++ksp) {
        const int e4 = ksp * 4;
        const unsigned int own0 = h1 ? pd[e4 + 2] : pd[e4 + 0];
        const unsigned int own1 = h1 ? pd[e4 + 3] : pd[e4 + 1];
        const unsigned int snd0 = h1 ? pd[e4 + 0] : pd[e4 + 2];
        const unsigned int snd1 = h1 ? pd[e4 + 1] : pd[e4 + 3];
        const unsigned int rcv0 = (unsigned int)__shfl_xor((int)snd0, 32);
        const unsigned int rcv1 = (unsigned int)__shfl_xor((int)snd1, 32);
        u4v pw;
        pw[0] = h1 ? rcv0 : own0;
        pw[1] = h1 ? rcv1 : own1;
        pw[2] = h1 ? own0 : rcv0;
        pw[3] = h1 ? own1 : rcv1;
        s8v pf = __builtin_bit_cast(s8v, pw);
#pragma unroll
        for (int dblk = 0; dblk < 4; ++dblk) {
          s8v vf = *(const s8v*)(shc + vVb + (vbo + ksp * 4096 + dblk * 512));
          oacc[dblk] = __builtin_amdgcn_mfma_f32_32x32x16_bf16(vf, pf, oacc[dblk], 0, 0, 0);
        }
      }
    }

    if (more) __syncthreads();  // drain DMA(kb+1) + guard buffer reuse
  };

  for (int kb = 0; kb < nkb; kb += 2) {
    body(kb, 0);
    body(kb + 1, 16384);
  }

  // ---- epilogue: normalize, store fp32 directly
  const float lt = l_i + __shfl_xor(l_i, 32);
  const float inv = 1.0f / lt;
  float* op = Ob + (size_t)qrow * 128;
#pragma unroll
  for (int dblk = 0; dblk < 4; ++dblk)
#pragma unroll
    for (int gg = 0; gg < 4; ++gg) {
      float4 st;
      st.x = oacc[dblk][4 * gg + 0] * inv;
      st.y = oacc[dblk][4 * gg + 1] * inv;
      st.z = oacc[dblk][4 * gg + 2] * inv;
      st.w = oacc[dblk][4 * gg + 3] * inv;
      *(float4*)(op + dblk * 32 + 8 * gg + 4 * hh) = st;
    }
}

extern "C" void kernel_launch(void* const* d_in, const int* in_sizes, int n_in,
                              void* d_out, int out_size, void* d_ws, size_t ws_size,
                              hipStream_t stream) {
  const float* q = (const float*)d_in[0];
  const float* k = (const float*)d_in[1];
  const float* v = (const float*)d_in[2];
  float* o = (float*)d_out;
  unsigned short* Kt = (unsigned short*)d_ws;        // 16 bk x 64 tiles x 8KB = 8MB
  unsigned short* Vt = Kt + (size_t)16 * 64 * 4096;  // +8MB
  prepack_kernel<<<dim3(1024), dim3(256), 0, stream>>>(k, v, Kt, Vt);
  gqa_attn_kernel<<<dim3(512), dim3(256), 0, stream>>>(q, Kt, Vt, o);
}